// Round 11
// baseline (3414.985 us; speedup 1.0000x reference)
//
#include <hip/hip_runtime.h>
#include <cstdint>
#include <cstddef>

#define B_   2
#define N_   8192
#define M_   2048
#define K_   32
#define C0_  64
#define C1_  128
#define C2_  256
#define CIN_ 67

// Exact-match distance: reference computes sum((a-b)**2, axis=-1) in f32 as
// ((dx^2 + dy^2) + dz^2) with no FMA contraction. _rn intrinsics forbid
// contract-fast fma fusion (would flip argmax / radius-boundary decisions).
__device__ __forceinline__ float sqdist_rn(float ax, float ay, float az,
                                           float bx, float by, float bz) {
  float dx = __fsub_rn(ax, bx);
  float dy = __fsub_rn(ay, by);
  float dz = __fsub_rn(az, bz);
  return __fadd_rn(__fadd_rn(__fmul_rn(dx, dx), __fmul_rn(dy, dy)),
                   __fmul_rn(dz, dz));
}

__device__ __forceinline__ int morton8(int ix, int iy, int iz) {
  int m = 0;
#pragma unroll
  for (int b = 0; b < 3; ++b) {
    m |= (((ix >> b) & 1) << (3 * b + 2)) | (((iy >> b) & 1) << (3 * b + 1)) |
         (((iz >> b) & 1) << (3 * b + 0));
  }
  return m;
}

// u64 max across the wave via paired DPP (row_shr 1/2/4/8, row_bcast 15/31);
// result broadcast via readlane(63). Tie-break baked into the key.
__device__ __forceinline__ unsigned long long wave_max_u64_dpp(unsigned long long k) {
#define FPS_STEP(ctrl)                                                         \
  {                                                                            \
    int klo = (int)(unsigned)k, khi = (int)(unsigned)(k >> 32);                \
    int olo = __builtin_amdgcn_update_dpp(klo, klo, ctrl, 0xf, 0xf, false);    \
    int ohi = __builtin_amdgcn_update_dpp(khi, khi, ctrl, 0xf, 0xf, false);    \
    unsigned long long ok =                                                    \
        ((unsigned long long)(unsigned)ohi << 32) | (unsigned)olo;             \
    if (ok > k) k = ok;                                                        \
  }
  FPS_STEP(0x111)  // row_shr:1
  FPS_STEP(0x112)  // row_shr:2
  FPS_STEP(0x114)  // row_shr:4
  FPS_STEP(0x118)  // row_shr:8
  FPS_STEP(0x142)  // row_bcast:15
  FPS_STEP(0x143)  // row_bcast:31
#undef FPS_STEP
  unsigned lo = (unsigned)__builtin_amdgcn_readlane((int)(unsigned)k, 63);
  unsigned hi = (unsigned)__builtin_amdgcn_readlane((int)(unsigned)(k >> 32), 63);
  return ((unsigned long long)hi << 32) | lo;
}

// LDS map (156416 B):
//   [0,      131072) spt    float4{x,y,z,bitcast pid}[8192]  (SETUP ONLY —
//                           the main loop does zero spt reads)
//   [131072, 155648) snew3  float[2048*3] winner-coord ring (write-only in
//                           loop; dumped at end). Overlays sort scratch
//                           hist[512]/boff[512]/wsum[8], dead before use.
//   [155648, 155904) sKeyP  u64[2][16]   parity-buffered wave key slots
//   [155904, 156416) sCrdP  float4[2][16] parity-buffered wave coord slots
// ---------------------------------------------------------------------------
// 1) FPS: 1024 thr = 16 waves (r6's proven shape), points + d[] in REGISTERS
//    (no body LDS reads, no bank conflicts), coords-in-slots, ONE barrier per
//    iteration, cheap replicated selection (~25 insts).
//    Thread t owns sorted pts [8t,8t+8) (Morton-contiguous bucket) with
//    bounding sphere (c,rad). Cached per-thread: tkey (bucket argmax key),
//    candidate coords (bcx..), skip threshold thrT. Cached per-wave: slot key
//    wk + coords (wcx..), rewritten to the parity slot every iteration.
//    Per iteration: sqrt-free conservative skip test -> dirty lanes redo
//    exact 8-pt register update -> dirty waves re-reduce (key-only DPP,
//    ballot+readlane coords) -> lane63 writes slots[it&1] -> barrier ->
//    ALL waves: read 16 key slots (8B stride: conflict-free) + coord slots
//    (16B stride: free 2-way), 4-step row-16 DPP key max, 2 readlanes ->
//    kmax, ballot+ff1 -> winner lane, 3 readlanes -> winner coords in
//    REGISTERS (no dependent spt/snew reads). t0 logs coords to snew3 ring.
//    Key = (d_bits<<26)|(8191-pid)<<13: u64 max == (max d, min ORIGINAL idx)
//    == jnp.argmax first-occurrence; pid unique -> deterministic despite
//    nondeterministic counting-sort scatter. Skipped buckets provably
//    unchanged (conservative threshold) -> d bit-exact vs reference.
// ---------------------------------------------------------------------------
__global__ __launch_bounds__(1024, 1) void fps_kernel(const float* __restrict__ xyz,
                                                      float* __restrict__ new_xyz) {
  __shared__ __align__(16) unsigned char ldsbuf[156416];
  float4* spt   = (float4*)(ldsbuf);
  float*  snew3 = (float*)(ldsbuf + 131072);
  int*    hist  = (int*)(ldsbuf + 131072);          // overlay (setup only)
  int*    boff  = (int*)(ldsbuf + 131072 + 2048);   // overlay (setup only)
  int*    wsum  = (int*)(ldsbuf + 131072 + 4096);   // overlay (setup only)
  unsigned long long* sKeyP = (unsigned long long*)(ldsbuf + 155648);
  float4* sCrdP = (float4*)(ldsbuf + 155904);

  const int b = blockIdx.x;
  const int t = threadIdx.x;
  const int lane = t & 63;
  const int w = t >> 6;
  const float* xb = xyz + (size_t)b * N_ * 3;

  // ---- counting sort by 8^3 morton cell (1024 thr, 8 pts each) ----
  if (t < 512) hist[t] = 0;
  __syncthreads();
#pragma unroll
  for (int rr = 0; rr < 8; ++rr) {
    int i = rr * 1024 + t;
    float X = xb[i * 3 + 0], Y = xb[i * 3 + 1], Z = xb[i * 3 + 2];
    int ix = min(7, max(0, (int)(X * 8.0f)));
    int iy = min(7, max(0, (int)(Y * 8.0f)));
    int iz = min(7, max(0, (int)(Z * 8.0f)));
    atomicAdd(&hist[morton8(ix, iy, iz)], 1);
  }
  __syncthreads();
  // exclusive scan of 512 bins (8 active waves)
  {
    int ov = (t < 512) ? hist[t] : 0;
    int v = ov;
#pragma unroll
    for (int off = 1; off < 64; off <<= 1) {
      int n = __shfl_up(v, off);
      if (lane >= off) v += n;
    }
    if (t < 512 && lane == 63) wsum[w] = v;
    __syncthreads();
    if (t == 0) {
      int acc = 0;
#pragma unroll
      for (int j = 0; j < 8; ++j) { int x0 = wsum[j]; wsum[j] = acc; acc += x0; }
    }
    __syncthreads();
    if (t < 512) boff[t] = v - ov + wsum[w];
  }
  __syncthreads();
#pragma unroll
  for (int rr = 0; rr < 8; ++rr) {
    int i = rr * 1024 + t;
    float X = xb[i * 3 + 0], Y = xb[i * 3 + 1], Z = xb[i * 3 + 2];
    int ix = min(7, max(0, (int)(X * 8.0f)));
    int iy = min(7, max(0, (int)(Y * 8.0f)));
    int iz = min(7, max(0, (int)(Z * 8.0f)));
    int pos = atomicAdd(&boff[morton8(ix, iy, iz)], 1);
    float4 v4; v4.x = X; v4.y = Y; v4.z = Z; v4.w = __int_as_float(i);
    spt[pos] = v4;
  }
  __syncthreads();  // scatter done; hist/boff dead -> snew3 region usable

  // ---- per-thread bucket into registers ----
  float px[8], py[8], pz[8], d[8];
  unsigned lowk[8];
#pragma unroll
  for (int k = 0; k < 8; ++k) {
    float4 v4 = spt[8 * t + k];
    px[k] = v4.x; py[k] = v4.y; pz[k] = v4.z;
    int pid = __float_as_int(v4.w);
    lowk[k] = (unsigned)(8191 - pid) << 13;
    d[k] = 1e10f;  // == f32(10000000000.0), matches jnp init exactly
  }
  float cx = 0.f, cy = 0.f, cz = 0.f;
#pragma unroll
  for (int k = 0; k < 8; ++k) { cx += px[k]; cy += py[k]; cz += pz[k]; }
  cx *= 0.125f; cy *= 0.125f; cz *= 0.125f;
  float r2m = 0.f;
#pragma unroll
  for (int k = 0; k < 8; ++k) {
    float dx = px[k] - cx, dy = py[k] - cy, dz = pz[k] - cz;
    r2m = fmaxf(r2m, dx * dx + dy * dy + dz * dz);
  }
  const float rad = sqrtf(r2m) * 1.00002f + 1e-12f;

  // cached state (see header comment)
  unsigned long long tkey = 0ull, wk = 0ull;
  float thrT = 3e38f;                       // never skip before first update
  float bcx = px[0], bcy = py[0], bcz = pz[0];
  float wcx = 0.f, wcy = 0.f, wcz = 0.f;

  float lx = xb[0], ly = xb[1], lz = xb[2];  // first selected index = 0
  if (t == 0) { snew3[0] = lx; snew3[1] = ly; snew3[2] = lz; }

  for (int it = 1; it < M_; ++it) {
    const int wp = it & 1;
    // ---- conservative skip test (sqrt-free clean path) ----
    float ex = lx - cx, ey = ly - cy, ez = lz - cz;
    float dc2 = ex * ex + ey * ey + ez * ez;
    bool dirtyLane = dc2 <= thrT;
    if (__ballot(dirtyLane) != 0ull) {  // wave-uniform: refresh wave slot
      if (dirtyLane) {
        unsigned long long nk = 0ull;
        float nx = bcx, ny = bcy, nz = bcz;
#pragma unroll
        for (int k = 0; k < 8; ++k) {
          float dist = sqdist_rn(px[k], py[k], pz[k], lx, ly, lz);
          float dm = fminf(d[k], dist);
          d[k] = dm;
          unsigned long long key =
              ((unsigned long long)(unsigned)__float_as_int(dm) << 26) | lowk[k];
          bool take = key > nk;
          nk = take ? key : nk;
          nx = take ? px[k] : nx;
          ny = take ? py[k] : ny;
          nz = take ? pz[k] : nz;
        }
        tkey = nk; bcx = nx; bcy = ny; bcz = nz;
        float bd = __int_as_float((int)(unsigned)(tkey >> 26));
        float sr = sqrtf(bd * 1.0001f) + rad;  // conservative: margins >> ulp
        thrT = sr * sr;
      }
      unsigned long long wkn = wave_max_u64_dpp(tkey);
      unsigned long long tied = __ballot(tkey == wkn);  // key unique -> 1 lane
      int src = __ffsll((long long)tied) - 1;
      wk = wkn;
      wcx = __builtin_amdgcn_readlane(__float_as_int(bcx), src) == 0
                ? __int_as_float(__builtin_amdgcn_readlane(__float_as_int(bcx), src))
                : __int_as_float(__builtin_amdgcn_readlane(__float_as_int(bcx), src));
      wcx = __int_as_float(__builtin_amdgcn_readlane(__float_as_int(bcx), src));
      wcy = __int_as_float(__builtin_amdgcn_readlane(__float_as_int(bcy), src));
      wcz = __int_as_float(__builtin_amdgcn_readlane(__float_as_int(bcz), src));
    }
    if (lane == 63) {
      sKeyP[wp * 16 + w] = wk;
      float4 c4; c4.x = wcx; c4.y = wcy; c4.z = wcz; c4.w = 0.f;
      sCrdP[wp * 16 + w] = c4;
    }
    __syncthreads();  // the ONLY barrier per iteration
    // ---- replicated selection: ~25 insts, no dependent 2nd LDS read ----
    {
      int sl = lane & 15;  // 4 rows x 16: each row holds all 16 slots
      unsigned long long korig = sKeyP[wp * 16 + sl];
      float4 c4 = sCrdP[wp * 16 + sl];
      unsigned long long kred = korig;
#define FPS_STEP2(ctrl)                                                        \
      {                                                                        \
        int klo = (int)(unsigned)kred, khi = (int)(unsigned)(kred >> 32);      \
        int olo = __builtin_amdgcn_update_dpp(klo, klo, ctrl, 0xf, 0xf, false);\
        int ohi = __builtin_amdgcn_update_dpp(khi, khi, ctrl, 0xf, 0xf, false);\
        unsigned long long okey =                                              \
            ((unsigned long long)(unsigned)ohi << 32) | (unsigned)olo;         \
        if (okey > kred) kred = okey;                                          \
      }
      FPS_STEP2(0x111)  // row_shr:1
      FPS_STEP2(0x112)  // row_shr:2
      FPS_STEP2(0x114)  // row_shr:4
      FPS_STEP2(0x118)  // row_shr:8
#undef FPS_STEP2
      unsigned mlo = (unsigned)__builtin_amdgcn_readlane((int)(unsigned)kred, 15);
      unsigned mhi = (unsigned)__builtin_amdgcn_readlane((int)(unsigned)(kred >> 32), 15);
      unsigned long long kmax = ((unsigned long long)mhi << 32) | mlo;
      unsigned long long tied2 = __ballot(korig == kmax);  // 4 lanes (1/row)
      int src2 = __ffsll((long long)tied2) - 1;            // lane in [0,16)
      lx = __int_as_float(__builtin_amdgcn_readlane(__float_as_int(c4.x), src2));
      ly = __int_as_float(__builtin_amdgcn_readlane(__float_as_int(c4.y), src2));
      lz = __int_as_float(__builtin_amdgcn_readlane(__float_as_int(c4.z), src2));
    }
    if (t == 0) {
      snew3[it * 3 + 0] = lx;
      snew3[it * 3 + 1] = ly;
      snew3[it * 3 + 2] = lz;
    }
  }
  __syncthreads();  // final snew3 writes visible

  // ---- coalesced dump of selected coords ----
  for (int i = t; i < M_ * 3; i += 1024) {
    new_xyz[(size_t)b * M_ * 3 + i] = snew3[i];
  }
}

// ---------------------------------------------------------------------------
// 2) Fused ball-query + grouping + MLP(67->128 relu ->256) + max over K.
//    One block (256 thr) per centroid. Ball query: wave w scans index chunk
//    [w*2048,(w+1)*2048) in order, ballot-appends first <=32 valid to its own
//    LDS list; lists concat in wave order == global index order (pointnet2
//    first-K semantics). Writes pre-BN pooled features TRANSPOSED into the
//    final (B,C2,M) output region (no scratch needed).
// ---------------------------------------------------------------------------
__global__ __launch_bounds__(256) void mlp_kernel(const float* __restrict__ xyz,
                                                  const float* __restrict__ x,
                                                  const float* __restrict__ W1,
                                                  const float* __restrict__ b1,
                                                  const float* __restrict__ W2,
                                                  const float* __restrict__ b2,
                                                  const float* __restrict__ new_xyz,
                                                  float* __restrict__ outp) {
  __shared__ float sGRed[32 * 69];   // group tile; unioned w/ 8x256 max-red
  __shared__ float sU[128 * 69];     // W1 staged; unioned w/ 32x256 W2 tile
  __shared__ float sH1[32 * 132];
  __shared__ int sWIdx[4][K_];
  __shared__ int sWCnt[4];
  __shared__ int sIdx[K_];
  __shared__ float sQ[3];

  const int gm = blockIdx.x;
  const int b = gm >> 11;    // M_ = 2048
  const int m = gm & 2047;
  const int t = threadIdx.x;
  const int lane = t & 63;
  const int w = t >> 6;
  const float* xb = xyz + (size_t)b * N_ * 3;

  if (t < 3) sQ[t] = new_xyz[(size_t)gm * 3 + t];
  __syncthreads();
  const float qx = sQ[0], qy = sQ[1], qz = sQ[2];
  // (float)(0.1*0.1) = 0x3C23D70A; 0.1f*0.1f rounds differently — wrong.
  const float R2 = (float)(0.1 * 0.1);

  // ---- ball query ----
  {
    int cnt = 0;
    const int cbeg = w * 2048, cend = cbeg + 2048;
    for (int base = cbeg; base < cend; base += 64) {
      int p = base + lane;
      float d2 = sqdist_rn(qx, qy, qz, xb[p * 3 + 0], xb[p * 3 + 1], xb[p * 3 + 2]);
      bool valid = d2 < R2;
      unsigned long long mask = __ballot(valid);
      if (valid) {
        int pos = cnt + __popcll(mask & ((1ull << lane) - 1ull));
        if (pos < K_) sWIdx[w][pos] = p;
      }
      cnt += __popcll(mask);
      if (cnt >= K_) break;  // wave-uniform
    }
    if (lane == 0) sWCnt[w] = (cnt < K_) ? cnt : K_;
  }
  __syncthreads();
  if (t < K_) {
    int c0 = sWCnt[0], c1 = sWCnt[1], c2 = sWCnt[2], c3 = sWCnt[3];
    int s1 = c0 + c1, s2 = s1 + c2, s3 = s2 + c3;
    int j = t, idx;
    if (j < c0) idx = sWIdx[0][j];
    else if (j < s1) idx = sWIdx[1][j - c0];
    else if (j < s2) idx = sWIdx[2][j - s1];
    else if (j < s3) idx = sWIdx[3][j - s2];
    else {
      int fw = c0 ? 0 : (c1 ? 1 : (c2 ? 2 : 3));
      idx = (s3 > 0) ? sWIdx[fw][0] : 0;  // fill with first valid index
    }
    sIdx[j] = idx;
  }
  __syncthreads();

  // ---- grouping: rel coords + features into sGRed (32 x 69 padded) ----
  if (t < K_) {
    int id = sIdx[t];
    sGRed[t * 69 + 0] = xb[id * 3 + 0] - qx;
    sGRed[t * 69 + 1] = xb[id * 3 + 1] - qy;
    sGRed[t * 69 + 2] = xb[id * 3 + 2] - qz;
  }
  {
    int r = t & 31;
    int c0 = (t >> 5) * 8;
    int id = sIdx[r];
    const float* xf = x + ((size_t)b * C0_ + c0) * N_ + id;
#pragma unroll
    for (int j = 0; j < 8; ++j) sGRed[r * 69 + 3 + c0 + j] = xf[(size_t)j * N_];
  }
  for (int i = t; i < C1_ * CIN_; i += 256) {
    sU[(i / CIN_) * 69 + (i % CIN_)] = W1[i];
  }
  __syncthreads();

  const int ol = t & 31;  // output-lane: o = ol + 32*j
  const int rg = t >> 5;  // row group: rows rg*4 .. rg*4+3

  // ---- layer 1: h1 = relu(G @ W1^T + b1), 4 rows x 4 outs per thread ----
  float acc[4][4] = {{0.f}};
  for (int c = 0; c < CIN_; ++c) {
    float g[4], wv[4];
#pragma unroll
    for (int i = 0; i < 4; ++i) g[i] = sGRed[(rg * 4 + i) * 69 + c];
#pragma unroll
    for (int j = 0; j < 4; ++j) wv[j] = sU[(ol + 32 * j) * 69 + c];
#pragma unroll
    for (int i = 0; i < 4; ++i)
#pragma unroll
      for (int j = 0; j < 4; ++j) acc[i][j] += g[i] * wv[j];
  }
#pragma unroll
  for (int j = 0; j < 4; ++j) {
    float bias = b1[ol + 32 * j];
#pragma unroll
    for (int i = 0; i < 4; ++i) {
      float v = acc[i][j] + bias;
      sH1[(rg * 4 + i) * 132 + ol + 32 * j] = fmaxf(v, 0.0f);
    }
  }

  // ---- layer 2: h2 = h1 @ W2^T, 4 rows x 8 outs per thread ----
  float acc2[4][8] = {{0.f}};
  for (int ct = 0; ct < 4; ++ct) {
    __syncthreads();  // sU reuse safe; (ct==0) also covers sH1 writes
    const float4* w4 = (const float4*)(W2 + (size_t)t * C1_ + ct * 32);
#pragma unroll
    for (int jj = 0; jj < 8; ++jj) {
      float4 v = w4[jj];
      sU[(jj * 4 + 0) * 256 + t] = v.x;
      sU[(jj * 4 + 1) * 256 + t] = v.y;
      sU[(jj * 4 + 2) * 256 + t] = v.z;
      sU[(jj * 4 + 3) * 256 + t] = v.w;
    }
    __syncthreads();
    for (int cc = 0; cc < 32; ++cc) {
      float h[4], wv[8];
#pragma unroll
      for (int i = 0; i < 4; ++i) h[i] = sH1[(rg * 4 + i) * 132 + ct * 32 + cc];
#pragma unroll
      for (int j = 0; j < 8; ++j) wv[j] = sU[cc * 256 + ol + 32 * j];
#pragma unroll
      for (int i = 0; i < 4; ++i)
#pragma unroll
        for (int j = 0; j < 8; ++j) acc2[i][j] += h[i] * wv[j];
    }
  }

  // ---- max over K, + b2 (max(x)+c == max(x+c): RN is monotone) ----
  __syncthreads();  // group tile dead; reuse sGRed as reduction buffer
#pragma unroll
  for (int j = 0; j < 8; ++j) {
    float pm = acc2[0][j];
#pragma unroll
    for (int i = 1; i < 4; ++i) pm = fmaxf(pm, acc2[i][j]);
    sGRed[rg * 256 + ol + 32 * j] = pm;
  }
  __syncthreads();
  {
    int o = t;
    float v = sGRed[o];
#pragma unroll
    for (int g = 1; g < 8; ++g) v = fmaxf(v, sGRed[g * 256 + o]);
    v += b2[o];
    // transposed store into final (B, C2, M) layout (pre-BN)
    outp[((size_t)(b * C2_ + o)) * M_ + m] = v;
  }
}

// ---------------------------------------------------------------------------
// 3) BN stats per channel (deterministic, double accum). One block / channel.
// ---------------------------------------------------------------------------
__global__ __launch_bounds__(256) void bn_stats_kernel(const float* __restrict__ outp,
                                                       const float* __restrict__ gamma,
                                                       float* __restrict__ stats) {
  const int o = blockIdx.x;
  const int t = threadIdx.x;
  double s = 0.0, s2 = 0.0;
  for (int b = 0; b < B_; ++b) {
    const float* p = outp + ((size_t)(b * C2_ + o)) * M_;
    for (int i = t; i < M_; i += 256) {
      float v = p[i];
      s += (double)v;
      s2 += (double)v * (double)v;
    }
  }
#pragma unroll
  for (int off = 32; off > 0; off >>= 1) {
    s += __shfl_xor(s, off);
    s2 += __shfl_xor(s2, off);
  }
  __shared__ double aS[4], aS2[4];
  if ((t & 63) == 0) { aS[t >> 6] = s; aS2[t >> 6] = s2; }
  __syncthreads();
  if (t == 0) {
    double S = aS[0] + aS[1] + aS[2] + aS[3];
    double S2 = aS2[0] + aS2[1] + aS2[2] + aS2[3];
    double mean = S / (double)(B_ * M_);
    double var = S2 / (double)(B_ * M_) - mean * mean;
    float rstd = 1.0f / sqrtf((float)var + 1e-5f);
    stats[o] = (float)mean;
    stats[C2_ + o] = gamma[o] * rstd;
  }
}

// ---------------------------------------------------------------------------
// 4) BN apply, in place on the (B,C2,M) output region. float4-vectorized.
// ---------------------------------------------------------------------------
__global__ __launch_bounds__(256) void bn_apply_kernel(float* __restrict__ outp,
                                                       const float* __restrict__ stats,
                                                       const float* __restrict__ beta) {
  const int i4 = blockIdx.x * 256 + threadIdx.x;  // B_*C2_*M_/4 = 262144
  const int ch = (i4 >> 9) & 255;                 // M_/4 = 512 float4 / chan
  const float mean = stats[ch];
  const float scale = stats[C2_ + ch];
  const float bt = beta[ch];
  float4 v = ((const float4*)outp)[i4];
  v.x = (v.x - mean) * scale + bt;
  v.y = (v.y - mean) * scale + bt;
  v.z = (v.z - mean) * scale + bt;
  v.w = (v.w - mean) * scale + bt;
  ((float4*)outp)[i4] = v;
}

// ---------------------------------------------------------------------------
extern "C" void kernel_launch(void* const* d_in, const int* in_sizes, int n_in,
                              void* d_out, int out_size, void* d_ws, size_t ws_size,
                              hipStream_t stream) {
  const float* xyz   = (const float*)d_in[0];
  const float* x     = (const float*)d_in[1];
  const float* W1    = (const float*)d_in[2];
  const float* b1    = (const float*)d_in[3];
  const float* W2    = (const float*)d_in[4];
  const float* b2    = (const float*)d_in[5];
  const float* gamma = (const float*)d_in[6];
  const float* beta  = (const float*)d_in[7];

  float* new_xyz = (float*)d_out;                       // (B, M, 3)
  float* outp    = (float*)d_out + (size_t)B_ * M_ * 3; // (B, C2, M)
  float* stats   = (float*)d_ws;                        // 2*C2 floats = 2 KB

  fps_kernel<<<B_, 1024, 0, stream>>>(xyz, new_xyz);
  mlp_kernel<<<B_ * M_, 256, 0, stream>>>(xyz, x, W1, b1, W2, b2, new_xyz, outp);
  bn_stats_kernel<<<C2_, 256, 0, stream>>>(outp, gamma, stats);
  bn_apply_kernel<<<(B_ * C2_ * M_ / 4) / 256, 256, 0, stream>>>(outp, stats, beta);
}